// Round 2
// baseline (1786.577 us; speedup 1.0000x reference)
//
#include <hip/hip_runtime.h>
#include <math.h>

#define DIM   4096
#define NITER 20
#define EPSF  1e-10f
#define NB    256
#define NT    1024
#define NRG   16   // fallback path

// ================= two-level grid barrier (agent scope, cross-XCD safe) ==========
__device__ __forceinline__ void gridbarrier(unsigned* bar, int b) {
    __syncthreads();
    if (threadIdx.x == 0) {
        unsigned* gen  = bar;               // 64B-spaced slots
        unsigned* root = bar + 16;
        unsigned* cnt  = bar + 32 + 16 * (b & 7);
        unsigned g = __hip_atomic_load(gen, __ATOMIC_RELAXED, __HIP_MEMORY_SCOPE_AGENT);
        bool winner = false;
        unsigned a = __hip_atomic_fetch_add(cnt, 1u, __ATOMIC_ACQ_REL, __HIP_MEMORY_SCOPE_AGENT);
        if (a == 31u) {  // 256 blocks / 8 counters = 32 arrivals each
            unsigned a2 = __hip_atomic_fetch_add(root, 1u, __ATOMIC_ACQ_REL, __HIP_MEMORY_SCOPE_AGENT);
            if (a2 == 7u) {
                __hip_atomic_store(root, 0u, __ATOMIC_RELAXED, __HIP_MEMORY_SCOPE_AGENT);
                for (int i = 0; i < 8; ++i)
                    __hip_atomic_store(bar + 32 + 16 * i, 0u, __ATOMIC_RELAXED, __HIP_MEMORY_SCOPE_AGENT);
                __hip_atomic_fetch_add(gen, 1u, __ATOMIC_RELEASE, __HIP_MEMORY_SCOPE_AGENT);
                winner = true;
            }
        }
        if (!winner) {
            while (__hip_atomic_load(gen, __ATOMIC_ACQUIRE, __HIP_MEMORY_SCOPE_AGENT) == g)
                __builtin_amdgcn_s_sleep(1);
        }
    }
    __syncthreads();
}

__global__ void zero_bar(unsigned* bar) {
    if (threadIdx.x < 256) bar[threadIdx.x] = 0u;
}

// ================= persistent Sinkhorn: matrix lives in registers ================
__global__ __launch_bounds__(NT, 4) void sinkhorn_persistent(
        const float* __restrict__ logits, const float* __restrict__ noise,
        float* __restrict__ out, float* __restrict__ c, unsigned* __restrict__ bar) {
    __shared__ float wred[16][17];
    __shared__ float Mbc[16];
    __shared__ float rbc[16];

    const int t = threadIdx.x;
    const int b = blockIdx.x;
    const int wave = t >> 6, lane = t & 63;
    const int g0 = b * 16;                 // block's first row
    float* part = out;                     // first 4 MiB of out = partial scratch

    // ---- init: L0 into registers (read HBM once, never again) ----
    float4 v[16];
#pragma unroll
    for (int r = 0; r < 16; ++r) {
        const float4 l = *(const float4*)(logits + (size_t)(g0 + r) * DIM + 4 * t);
        const float4 u = *(const float4*)(noise  + (size_t)(g0 + r) * DIM + 4 * t);
        v[r].x = l.x - __logf(-__logf(u.x + EPSF) + EPSF);
        v[r].y = l.y - __logf(-__logf(u.y + EPSF) + EPSF);
        v[r].z = l.z - __logf(-__logf(u.z + EPSF) + EPSF);
        v[r].w = l.w - __logf(-__logf(u.w + EPSF) + EPSF);
    }
    float4 cc = make_float4(0.f, 0.f, 0.f, 0.f);
    float rr[16];

    for (int it = 0; it < NITER; ++it) {
        // ---------- row LSE (block-local): rr[r] = LSE_j(v - c) ----------
#pragma unroll
        for (int r = 0; r < 16; ++r) {
            float m = fmaxf(fmaxf(v[r].x - cc.x, v[r].y - cc.y),
                            fmaxf(v[r].z - cc.z, v[r].w - cc.w));
#pragma unroll
            for (int o = 32; o > 0; o >>= 1) m = fmaxf(m, __shfl_down(m, o, 64));
            if (lane == 0) wred[r][wave] = m;
        }
        __syncthreads();
        if (t < 16) {
            float M = wred[t][0];
#pragma unroll
            for (int i = 1; i < 16; ++i) M = fmaxf(M, wred[t][i]);
            Mbc[t] = M;
        }
        __syncthreads();
#pragma unroll
        for (int r = 0; r < 16; ++r) {
            const float M = Mbc[r];
            float s = __expf(v[r].x - cc.x - M) + __expf(v[r].y - cc.y - M)
                    + __expf(v[r].z - cc.z - M) + __expf(v[r].w - cc.w - M);
#pragma unroll
            for (int o = 32; o > 0; o >>= 1) s += __shfl_down(s, o, 64);
            if (lane == 0) wred[r][wave] = s;
        }
        __syncthreads();
        if (t < 16) {
            float S = 0.f;
#pragma unroll
            for (int i = 0; i < 16; ++i) S += wred[t][i];
            rbc[t] = Mbc[t] + __logf(S);
        }
        __syncthreads();
#pragma unroll
        for (int r = 0; r < 16; ++r) rr[r] = rbc[r];

        // ---------- col partial LSE (thread-local over 16 rows) ----------
        float4 pl;
#define COL_PARTIAL(comp, dst)                                           \
        {                                                                \
            float m = v[0].comp - rr[0];                                 \
            _Pragma("unroll")                                            \
            for (int r2 = 1; r2 < 16; ++r2)                              \
                m = fmaxf(m, v[r2].comp - rr[r2]);                       \
            float s = 0.f;                                               \
            _Pragma("unroll")                                            \
            for (int r2 = 0; r2 < 16; ++r2)                              \
                s += __expf(v[r2].comp - rr[r2] - m);                    \
            dst = m + __logf(s);                                         \
        }
        COL_PARTIAL(x, pl.x)
        COL_PARTIAL(y, pl.y)
        COL_PARTIAL(z, pl.z)
        COL_PARTIAL(w, pl.w)
#undef COL_PARTIAL
        *(float4*)(part + (size_t)b * DIM + 4 * t) = pl;

        gridbarrier(bar, b);

        // ---------- combine: block b -> c[16b + wave] over 256 partials ----------
        {
            const int jj = g0 + wave;
            const float p0 = part[(size_t)(lane      ) * DIM + jj];
            const float p1 = part[(size_t)(lane +  64) * DIM + jj];
            const float p2 = part[(size_t)(lane + 128) * DIM + jj];
            const float p3 = part[(size_t)(lane + 192) * DIM + jj];
            float m = fmaxf(fmaxf(p0, p1), fmaxf(p2, p3));
#pragma unroll
            for (int o = 1; o < 64; o <<= 1) m = fmaxf(m, __shfl_xor(m, o, 64));
            float s = __expf(p0 - m) + __expf(p1 - m) + __expf(p2 - m) + __expf(p3 - m);
#pragma unroll
            for (int o = 1; o < 64; o <<= 1) s += __shfl_xor(s, o, 64);
            if (lane == 0) c[jj] = m + __logf(s);
        }

        gridbarrier(bar, b);

        cc = *(const float4*)(c + 4 * t);   // fresh column offsets for next iter
    }

    // ---------- final: out = exp(L0 - r - c) ----------
#pragma unroll
    for (int r = 0; r < 16; ++r) {
        float4 o;
        o.x = __expf(v[r].x - rr[r] - cc.x);
        o.y = __expf(v[r].y - rr[r] - cc.y);
        o.z = __expf(v[r].z - rr[r] - cc.z);
        o.w = __expf(v[r].w - rr[r] - cc.w);
        *(float4*)(out + (size_t)(g0 + r) * DIM + 4 * t) = o;
    }
}

// =================== fallback pipeline (round-1, known-good) =====================
__device__ __forceinline__ float waveMaxF(float v) {
#pragma unroll
    for (int o = 32; o > 0; o >>= 1) v = fmaxf(v, __shfl_down(v, o, 64));
    return v;
}
__device__ __forceinline__ float waveSumF(float v) {
#pragma unroll
    for (int o = 32; o > 0; o >>= 1) v += __shfl_down(v, o, 64);
    return v;
}

__global__ __launch_bounds__(256) void init_k(const float* __restrict__ logits,
                                              const float* __restrict__ noise,
                                              float* __restrict__ L0,
                                              float* __restrict__ c) {
    int idx = blockIdx.x * blockDim.x + threadIdx.x;
    int stride = gridDim.x * blockDim.x;
    const float4* l4 = (const float4*)logits;
    const float4* n4 = (const float4*)noise;
    float4* o4 = (float4*)L0;
    for (int p = idx; p < DIM * DIM / 4; p += stride) {
        float4 l = l4[p];
        float4 u = n4[p];
        float4 o;
        o.x = l.x - __logf(-__logf(u.x + EPSF) + EPSF);
        o.y = l.y - __logf(-__logf(u.y + EPSF) + EPSF);
        o.z = l.z - __logf(-__logf(u.z + EPSF) + EPSF);
        o.w = l.w - __logf(-__logf(u.w + EPSF) + EPSF);
        o4[p] = o;
    }
    if (idx < DIM) c[idx] = 0.0f;
}

__global__ __launch_bounds__(256) void row_lse(const float* __restrict__ L0,
                                               const float* __restrict__ c,
                                               float* __restrict__ r) {
    __shared__ float red[8];
    const int row = blockIdx.x;
    const int t = threadIdx.x;
    const float4* a4 = (const float4*)(L0 + (size_t)row * DIM);
    const float4* c4 = (const float4*)c;
    float v[16];
    float m = -INFINITY;
#pragma unroll
    for (int k = 0; k < 4; ++k) {
        float4 a  = a4[t + k * 256];
        float4 cc = c4[t + k * 256];
        v[4 * k + 0] = a.x - cc.x;
        v[4 * k + 1] = a.y - cc.y;
        v[4 * k + 2] = a.z - cc.z;
        v[4 * k + 3] = a.w - cc.w;
        m = fmaxf(m, fmaxf(fmaxf(v[4 * k], v[4 * k + 1]), fmaxf(v[4 * k + 2], v[4 * k + 3])));
    }
    m = waveMaxF(m);
    const int lane = t & 63, wid = t >> 6;
    if (lane == 0) red[wid] = m;
    __syncthreads();
    const float bm = fmaxf(fmaxf(red[0], red[1]), fmaxf(red[2], red[3]));
    float s = 0.0f;
#pragma unroll
    for (int q = 0; q < 16; ++q) s += __expf(v[q] - bm);
    s = waveSumF(s);
    if (lane == 0) red[4 + wid] = s;
    __syncthreads();
    if (t == 0) r[row] = bm + __logf(red[4] + red[5] + red[6] + red[7]);
}

__global__ __launch_bounds__(1024) void col_partial(const float* __restrict__ L0,
                                                    const float* __restrict__ r,
                                                    float2* __restrict__ part) {
    __shared__ float sr[256];
    __shared__ float smm[1024];
    __shared__ float sms[1024];
    const int g = blockIdx.x, h = blockIdx.y;
    const int tc = threadIdx.x & 255;
    const int ln = threadIdx.x >> 8;
    if (threadIdx.x < 256) sr[threadIdx.x] = r[h * 256 + threadIdx.x];
    __syncthreads();
    const int j = g * 256 + tc;
    float m = -INFINITY, s = 0.0f;
#pragma unroll 4
    for (int k = 0; k < 64; ++k) {
        int ii = k * 4 + ln;
        float v = L0[(size_t)(h * 256 + ii) * DIM + j] - sr[ii];
        float nm = fmaxf(m, v);
        s = s * __expf(m - nm) + __expf(v - nm);
        m = nm;
    }
    smm[threadIdx.x] = m;
    sms[threadIdx.x] = s;
    __syncthreads();
    if (threadIdx.x < 256) {
        float m0 = smm[tc], m1 = smm[tc + 256], m2 = smm[tc + 512], m3 = smm[tc + 768];
        float M = fmaxf(fmaxf(m0, m1), fmaxf(m2, m3));
        float S = sms[tc] * __expf(m0 - M) + sms[tc + 256] * __expf(m1 - M) +
                  sms[tc + 512] * __expf(m2 - M) + sms[tc + 768] * __expf(m3 - M);
        part[h * DIM + j] = make_float2(M, S);
    }
}

__global__ __launch_bounds__(256) void col_combine(const float2* __restrict__ part,
                                                   float* __restrict__ c) {
    int j = blockIdx.x * 256 + threadIdx.x;
    float pm[NRG], ps[NRG];
    float M = -INFINITY;
#pragma unroll
    for (int h = 0; h < NRG; ++h) {
        float2 p = part[h * DIM + j];
        pm[h] = p.x; ps[h] = p.y;
        M = fmaxf(M, p.x);
    }
    float S = 0.0f;
#pragma unroll
    for (int h = 0; h < NRG; ++h) S += ps[h] * __expf(pm[h] - M);
    c[j] = M + __logf(S);
}

__global__ __launch_bounds__(256) void final_exp(float* __restrict__ L0,
                                                 const float* __restrict__ r,
                                                 const float* __restrict__ c) {
    const float4* c4 = (const float4*)c;
    float4* a4 = (float4*)L0;
    int idx = blockIdx.x * blockDim.x + threadIdx.x;
    int stride = gridDim.x * blockDim.x;
    for (int p = idx; p < DIM * DIM / 4; p += stride) {
        int i  = p >> 10;
        int j4 = p & 1023;
        float4 a = a4[p];
        float rrv = r[i];
        float4 ccv = c4[j4];
        a.x = __expf(a.x - rrv - ccv.x);
        a.y = __expf(a.y - rrv - ccv.y);
        a.z = __expf(a.z - rrv - ccv.z);
        a.w = __expf(a.w - rrv - ccv.w);
        a4[p] = a;
    }
}

// ====================================== launch ===================================
extern "C" void kernel_launch(void* const* d_in, const int* in_sizes, int n_in,
                              void* d_out, int out_size, void* d_ws, size_t ws_size,
                              hipStream_t stream) {
    const float* logits = (const float*)d_in[0];
    const float* noise  = (const float*)d_in[1];
    float* out = (float*)d_out;
    float* c   = (float*)d_ws;                          // 16 KiB
    unsigned* bar = (unsigned*)((char*)d_ws + 16384);   // 1 KiB barrier state

    zero_bar<<<1, 256, 0, stream>>>(bar);
    void* args[] = { (void*)&logits, (void*)&noise, (void*)&out, (void*)&c, (void*)&bar };
    hipError_t err = hipLaunchCooperativeKernel((const void*)sinkhorn_persistent,
                                                dim3(NB), dim3(NT), args, 0, stream);
    if (err != hipSuccess) {
        // fallback: round-1 multi-kernel pipeline (known-good)
        float* ws = (float*)d_ws;
        float*  r    = ws;
        float*  cf   = ws + DIM;
        float2* part = (float2*)(ws + 2 * DIM);
        init_k<<<4096, 256, 0, stream>>>(logits, noise, out, cf);
        for (int t = 0; t < NITER; ++t) {
            row_lse<<<DIM, 256, 0, stream>>>(out, cf, r);
            col_partial<<<dim3(16, 16), 1024, 0, stream>>>(out, r, part);
            col_combine<<<16, 256, 0, stream>>>(part, cf);
        }
        final_exp<<<4096, 256, 0, stream>>>(out, r, cf);
    }
}